// Round 3
// baseline (374.953 us; speedup 1.0000x reference)
//
#include <hip/hip_runtime.h>

typedef _Float16 f16;
typedef _Float16 f16x8 __attribute__((ext_vector_type(8)));
typedef _Float16 f16x4 __attribute__((ext_vector_type(4)));
typedef float f32x4 __attribute__((ext_vector_type(4)));

#define B 16
#define C 256
#define H 32
#define W 32
#define HW (H * W)
#define T_STEPS 8
#define EPS_GN 1e-5f
#define EPS_NORM 1e-12f
#define N_ELEM ((size_t)B * C * HW)

// async global->LDS, 16B per lane; LDS dest is wave-uniform base + lane*16
__device__ inline void gld_lds16(const f16* g, f16* l) {
    __builtin_amdgcn_global_load_lds(
        (const __attribute__((address_space(1))) void*)g,
        (__attribute__((address_space(3))) void*)l, 16, 0, 0);
}

// ---------------- zero the energy region ----------------
__global__ void zero_es_kernel(float* es) {
    int i = threadIdx.x;
    if (i < (T_STEPS + 1) * B) es[i] = 0.0f;
}

// ---------------- GroupNorm(c)*gn_w + gn_b + conv_b -> c_hat (f32, NHWC) ----
__global__ __launch_bounds__(256) void gn_kernel(
    const float* __restrict__ c, const float* __restrict__ gn_w,
    const float* __restrict__ gn_b, const float* __restrict__ conv_b,
    float* __restrict__ c_hat) {
    int blk = blockIdx.x;          // b*64 + g
    int b = blk >> 6, g = blk & 63;
    const float* src = c + ((size_t)(b * C + 4 * g)) * HW;
    float sum = 0.f, sq = 0.f;
    for (int i = threadIdx.x; i < 4 * HW; i += 256) {
        float v = src[i];
        sum += v; sq += v * v;
    }
    #pragma unroll
    for (int o = 32; o > 0; o >>= 1) {
        sum += __shfl_down(sum, o, 64);
        sq  += __shfl_down(sq, o, 64);
    }
    __shared__ float s1[4], s2[4];
    if ((threadIdx.x & 63) == 0) { s1[threadIdx.x >> 6] = sum; s2[threadIdx.x >> 6] = sq; }
    __syncthreads();
    sum = s1[0] + s1[1] + s1[2] + s1[3];
    sq  = s2[0] + s2[1] + s2[2] + s2[3];
    float mean = sum * (1.0f / (4 * HW));
    float var  = sq  * (1.0f / (4 * HW)) - mean * mean;
    float scale = rsqrtf(var + EPS_GN);
    float wk[4], bk[4];
    #pragma unroll
    for (int k = 0; k < 4; k++) {
        wk[k] = gn_w[4 * g + k] * scale;
        bk[k] = gn_b[4 * g + k] + conv_b[4 * g + k];
    }
    for (int pix = threadIdx.x; pix < HW; pix += 256) {
        f32x4 o;
        #pragma unroll
        for (int k = 0; k < 4; k++)
            o[k] = (src[k * HW + pix] - mean) * wk[k] + bk[k];
        *reinterpret_cast<f32x4*>(c_hat + ((size_t)(b * HW + pix)) * C + 4 * g) = o;
    }
}

// ---------------- initial x normalize: f32 x0 (NCHW) + f16 copy (NHWC) -----
__global__ __launch_bounds__(256) void normx_kernel(
    const float* __restrict__ x, float* __restrict__ x0, f16* __restrict__ xh) {
    int gid = blockIdx.x * 256 + threadIdx.x;   // (b, g, pix)
    int b = gid >> 16;
    int rem = gid & 65535;
    int g = rem >> 10, pix = rem & 1023;
    size_t base = ((size_t)(b * C + 4 * g)) * HW + pix;
    float v0 = x[base], v1 = x[base + HW], v2 = x[base + 2 * HW], v3 = x[base + 3 * HW];
    float nrm = sqrtf(v0 * v0 + v1 * v1 + v2 * v2 + v3 * v3);
    float inv = 1.0f / fmaxf(nrm, EPS_NORM);
    v0 *= inv; v1 *= inv; v2 *= inv; v3 *= inv;
    x0[base] = v0; x0[base + HW] = v1; x0[base + 2 * HW] = v2; x0[base + 3 * HW] = v3;
    f16x4 hv = {(f16)v0, (f16)v1, (f16)v2, (f16)v3};
    *reinterpret_cast<f16x4*>(xh + ((size_t)(b * HW + pix)) * C + 4 * g) = hv;
}

// ------- weight permute: conv_w [co][ci][3][3] f32 -> wh2 [khkw][ci/8][co][8] f16
__global__ __launch_bounds__(256) void wconvert_kernel(
    const float* __restrict__ cw, f16* __restrict__ wh2) {
    int idx = blockIdx.x * 256 + threadIdx.x;   // k*2^16 | oct*2^11 | co*2^3 | j
    int j   = idx & 7;
    int co  = (idx >> 3) & 255;
    int oct = (idx >> 11) & 31;
    int k   = idx >> 16;
    int ci  = oct * 8 + j;
    wh2[idx] = (f16)cw[((size_t)(co * C + ci)) * 9 + k];
}

// ---------------- fused MFMA conv + oscillator update ----------------------
// 256 blocks (1/CU): block = (b, 64 co, 8 rows x 32 cols). 4 waves, each
// 64co x 64pix -> 4x4 frags of 16x16x32. K = 8 chunks of 32 ci x 9 khkw.
// Double-buffered LDS; W staged via global_load_lds; X reg-staged (NHWC src).
__global__ __launch_bounds__(256, 1) void conv_update_kernel(
    const f16* __restrict__ xh, const f16* __restrict__ wh2,
    const float* __restrict__ c_hat, const float* __restrict__ x_prev,
    const float* __restrict__ omg, const float* __restrict__ gamma_p,
    float* __restrict__ xs_out, f16* __restrict__ xh_out,
    float* __restrict__ es_b) {
    __shared__ f16 Xs[2][4][10][35][8];   // [buf][ci-oct][row][col(-1..33)][8ci]
    __shared__ f16 Ws[2][9][4][64][8];    // [buf][khkw][ci-oct][co][8ci]
    __shared__ float red[4];

    const int bid  = blockIdx.x;
    const int b    = bid >> 4;
    const int cot  = (bid >> 2) & 3;
    const int rowt = bid & 3;
    const int co0  = cot * 64;
    const int h0   = rowt * 8;
    const int tid  = threadIdx.x;
    const int lane = tid & 63;
    const int wv   = tid >> 6;
    const int n16  = lane & 15;
    const int grp  = lane >> 4;

    // zero halo cols (0, 33, 34) both buffers; zero OOB halo rows for edge tiles
    {
        f16x8 z = {};
        for (int u = tid; u < 240; u += 256) {
            int buf = u / 120, v = u % 120;
            int g = v / 30, w2 = v % 30;
            int r = w2 / 3, cc = w2 % 3;
            int col = (cc == 0) ? 0 : (32 + cc);
            *reinterpret_cast<f16x8*>(&Xs[buf][g][r][col][0]) = z;
        }
        if (rowt == 0 || rowt == 3) {
            int r = (rowt == 0) ? 0 : 9;
            for (int u = tid; u < 280; u += 256) {
                int buf = u / 140, v = u % 140;
                int g = v / 35, col = v % 35;
                *reinterpret_cast<f16x8*>(&Xs[buf][g][r][col][0]) = z;
            }
        }
    }

    // X staging map: 5 units/thread: L = tid + 256s -> (grp, col, row)
    int xr_r[5], xr_col[5], xr_g[5];
    bool xr_ok[5];
    #pragma unroll
    for (int s = 0; s < 5; s++) {
        int L = tid + 256 * s;
        xr_g[s] = L & 3; xr_col[s] = (L >> 2) & 31; xr_r[s] = L >> 7;
        int row = h0 - 1 + xr_r[s];
        xr_ok[s] = (row >= 0 && row < 32);
    }
    f16x8 xreg[5];

    #define LOAD_X(cb)                                                          \
        _Pragma("unroll")                                                       \
        for (int s = 0; s < 5; s++)                                             \
            if (xr_ok[s])                                                       \
                xreg[s] = *reinterpret_cast<const f16x8*>(                      \
                    xh + ((size_t)(b * HW + (h0 - 1 + xr_r[s]) * W + xr_col[s])) * C \
                       + (cb) * 32 + xr_g[s] * 8);

    #define WRITE_X(buf)                                                        \
        _Pragma("unroll")                                                       \
        for (int s = 0; s < 5; s++)                                             \
            if (xr_ok[s])                                                       \
                *reinterpret_cast<f16x8*>(&Xs[buf][xr_g[s]][xr_r[s]][xr_col[s] + 1][0]) = xreg[s];

    // W staging: wave wv stages ci-oct = wv for all 9 khkw, 1KB per glld
    #define STAGE_W(cb, buf)                                                    \
        _Pragma("unroll")                                                       \
        for (int k = 0; k < 9; k++)                                             \
            gld_lds16(wh2 + (((size_t)(k * 32 + (cb) * 4 + wv)) * C + co0 + lane) * 8, \
                      &Ws[buf][k][wv][0][0]);

    f32x4 acc[4][4];
    #pragma unroll
    for (int mt = 0; mt < 4; mt++)
        #pragma unroll
        for (int nt = 0; nt < 4; nt++) acc[mt][nt] = {0.f, 0.f, 0.f, 0.f};

    // prologue: stage chunk 0
    STAGE_W(0, 0);
    LOAD_X(0);
    WRITE_X(0);
    __syncthreads();   // drains vmcnt(0) (glld) + lgkmcnt (ds_writes)

    #pragma unroll
    for (int cb = 0; cb < 8; cb++) {
        const int cur = cb & 1;
        if (cb < 7) {
            STAGE_W(cb + 1, cur ^ 1);
            LOAD_X(cb + 1);
        }
        #pragma unroll
        for (int khkw = 0; khkw < 9; khkw++) {
            const int kh = khkw / 3, kw = khkw % 3;
            f16x8 af[4], bf[4];
            #pragma unroll
            for (int mt = 0; mt < 4; mt++)
                af[mt] = *reinterpret_cast<const f16x8*>(
                    &Ws[cur][khkw][grp][mt * 16 + n16][0]);
            #pragma unroll
            for (int nt = 0; nt < 4; nt++) {
                const int p = wv * 64 + nt * 16 + n16;
                bf[nt] = *reinterpret_cast<const f16x8*>(
                    &Xs[cur][grp][(p >> 5) + kh][(p & 31) + kw][0]);
            }
            #pragma unroll
            for (int mt = 0; mt < 4; mt++)
                #pragma unroll
                for (int nt = 0; nt < 4; nt++)
                    acc[mt][nt] = __builtin_amdgcn_mfma_f32_16x16x32_f16(
                        af[mt], bf[nt], acc[mt][nt], 0, 0, 0);
        }
        if (cb < 7) WRITE_X(cur ^ 1);
        __syncthreads();
    }

    // ---------------- epilogue: fused oscillator update ----------------
    const float gam = gamma_p[0];
    float e = 0.0f;
    #pragma unroll
    for (int mt = 0; mt < 4; mt++) {
        // D-frag: row(co) = grp*4 + reg, col(pix) = n16
        const int co = co0 + mt * 16 + grp * 4;
        const float a0 = omg[co], a1 = omg[co + 1];
        const float a2 = omg[co + 2], a3 = omg[co + 3];
        const float o0 = sqrtf(a0 * a0 + a1 * a1);
        const float o1 = sqrtf(a2 * a2 + a3 * a3);
        #pragma unroll
        for (int nt = 0; nt < 4; nt++) {
            const int p = wv * 64 + nt * 16 + n16;
            const int pix = h0 * W + p;
            const size_t basen = ((size_t)(b * C + co)) * HW + pix;  // NCHW
            const size_t basec = ((size_t)(b * HW + pix)) * C + co;  // NHWC
            f32x4 ch = *reinterpret_cast<const f32x4*>(c_hat + basec);
            float y0 = acc[mt][nt][0] + ch[0];
            float y1 = acc[mt][nt][1] + ch[1];
            float y2 = acc[mt][nt][2] + ch[2];
            float y3 = acc[mt][nt][3] + ch[3];
            float x0 = x_prev[basen],          x1 = x_prev[basen + HW];
            float x2 = x_prev[basen + 2 * HW], x3 = x_prev[basen + 3 * HW];
            float s = x0 * y0 + x1 * y1 + x2 * y2 + x3 * y3;
            float d0 =  o0 * x1 + y0 - s * x0;
            float d1 = -o0 * x0 + y1 - s * x1;
            float d2 =  o1 * x3 + y2 - s * x2;
            float d3 = -o1 * x2 + y3 - s * x3;
            float n0 = x0 + gam * d0, n1 = x1 + gam * d1;
            float n2 = x2 + gam * d2, n3 = x3 + gam * d3;
            float nrm = sqrtf(n0 * n0 + n1 * n1 + n2 * n2 + n3 * n3);
            float inv = 1.0f / fmaxf(nrm, EPS_NORM);
            n0 *= inv; n1 *= inv; n2 *= inv; n3 *= inv;
            xs_out[basen]          = n0; xs_out[basen + HW]     = n1;
            xs_out[basen + 2 * HW] = n2; xs_out[basen + 3 * HW] = n3;
            f16x4 hx = {(f16)n0, (f16)n1, (f16)n2, (f16)n3};
            *reinterpret_cast<f16x4*>(xh_out + basec) = hx;
            e -= s;
        }
    }
    #pragma unroll
    for (int o = 32; o > 0; o >>= 1) e += __shfl_down(e, o, 64);
    if (lane == 0) red[wv] = e;
    __syncthreads();
    if (tid == 0) atomicAdd(es_b + b, red[0] + red[1] + red[2] + red[3]);
}

extern "C" void kernel_launch(void* const* d_in, const int* in_sizes, int n_in,
                              void* d_out, int out_size, void* d_ws, size_t ws_size,
                              hipStream_t stream) {
    const float* x        = (const float*)d_in[0];
    const float* c        = (const float*)d_in[1];
    // d_in[2] = T (int scalar, known = 8)
    const float* gamma_p  = (const float*)d_in[3];
    const float* conv_w   = (const float*)d_in[4];
    const float* conv_b   = (const float*)d_in[5];
    const float* gn_w     = (const float*)d_in[6];
    const float* gn_b     = (const float*)d_in[7];
    const float* omg_par  = (const float*)d_in[8];

    float* out = (float*)d_out;
    float* es  = out + (size_t)T_STEPS * N_ELEM;   // (T+1, B) region

    // ws: c_hat f32 NHWC (16MB) | xh0 f16 NHWC (8MB) | xh1 (8MB) | wh2 (1.2MB)
    float* c_hat = (float*)d_ws;
    f16* xh0 = (f16*)(c_hat + N_ELEM);
    f16* xh1 = xh0 + N_ELEM;
    f16* wh2 = xh1 + N_ELEM;
    // f32 x0 (NCHW) borrows the xs[7] output slot (overwritten only at t=7)
    float* x0f = out + (size_t)(T_STEPS - 1) * N_ELEM;

    zero_es_kernel<<<1, 256, 0, stream>>>(es);
    gn_kernel<<<B * 64, 256, 0, stream>>>(c, gn_w, gn_b, conv_b, c_hat);
    normx_kernel<<<(B * 64 * HW) / 256, 256, 0, stream>>>(x, x0f, xh0);
    wconvert_kernel<<<(9 * C * C) / 256, 256, 0, stream>>>(conv_w, wh2);

    f16* xh_bufs[2] = {xh0, xh1};
    const float* xp = x0f;
    for (int t = 0; t < T_STEPS; t++) {
        float* xs_t = out + (size_t)t * N_ELEM;
        conv_update_kernel<<<256, 256, 0, stream>>>(
            xh_bufs[t & 1], wh2, c_hat, xp, omg_par, gamma_p,
            xs_t, xh_bufs[(t + 1) & 1], es + (size_t)(t + 1) * B);
        xp = xs_t;
    }
}